// Round 1
// baseline (140.344 us; speedup 1.0000x reference)
//
#include <hip/hip_runtime.h>

// PrototypicalNetwork: out[q,c] = -1/8 * sum_b sqrt(max(q2[q] + p2[b,c] - 2*qp[b,q,c], 0))
// Strategy: bf16 MFMA (16x16x32) for the qp GEMM (M=65536, N=1024, K=128),
// protos pre-swizzled to fragment-major layout in d_ws, barrier-free main loop.

#define DIM   128
#define NCLS  128
#define SHOTS 32
#define NB    8
#define NQ    65536

using short8 = __attribute__((ext_vector_type(8))) short;
using f32x4  = __attribute__((ext_vector_type(4))) float;

__device__ __forceinline__ unsigned short f2bf(float x) {
  union { float f; unsigned u; } v; v.f = x;
  unsigned r = v.u + 0x7fffu + ((v.u >> 16) & 1u);   // round-to-nearest-even
  return (unsigned short)(r >> 16);
}

__device__ __forceinline__ float fast_sqrt(float x) {
#if __has_builtin(__builtin_amdgcn_sqrtf)
  return __builtin_amdgcn_sqrtf(x);
#else
  return sqrtf(x);
#endif
}

// ---------------------------------------------------------------------------
// Kernel 1: protos (bootstrap-mean) -> bf16 in MFMA B-fragment-major layout,
// plus p2[b,c] = ||proto||^2 in fp32.
// Fragment layout for 16x16x32 bf16 B-operand: lane holds B[n=lane&15][k=(lane>>4)*8+j].
// Slot = (b*8 + ct)*4 + kiter; each slot is 64 lanes * 16 B = 1 KB contiguous.
// ---------------------------------------------------------------------------
__global__ __launch_bounds__(128) void proto_kernel(
    const float* __restrict__ sup, const int* __restrict__ bidx,
    unsigned short* __restrict__ pfrag, float* __restrict__ p2) {
  int bc = blockIdx.x;            // b*128 + c
  int c  = bc & (NCLS - 1);
  int d  = threadIdx.x;           // 0..127 = feature dim
  __shared__ int   sidx[SHOTS];
  __shared__ float red[DIM];
  if (d < SHOTS) sidx[d] = bidx[bc * SHOTS + d];
  __syncthreads();
  float acc = 0.f;
  const float* base = sup + c * SHOTS * DIM + d;
  #pragma unroll
  for (int s = 0; s < SHOTS; ++s) acc += base[sidx[s] * DIM];
  float proto = acc * (1.0f / 32.0f);

  int b     = bc >> 7;
  int ct    = c >> 4, l15c = c & 15;
  int kiter = d >> 5, quad = (d >> 3) & 3, j = d & 7;
  int lane  = l15c + (quad << 4);
  int slot  = (b * 8 + ct) * 4 + kiter;
  pfrag[slot * 512 + lane * 8 + j] = f2bf(proto);

  red[d] = proto * proto;          // p2 from fp32 protos (matches reference)
  __syncthreads();
  #pragma unroll
  for (int off = 64; off > 0; off >>= 1) {
    if (d < off) red[d] += red[d + off];
    __syncthreads();
  }
  if (d == 0) p2[bc] = red[0];
}

// ---------------------------------------------------------------------------
// Kernel 2: per block: 64 query rows x 128 classes.
// 4 waves: wave = (ctg<<1)|mtg; wave owns m-tiles {2*mtg, 2*mtg+1} and
// c-tiles {4*ctg .. 4*ctg+3}. Q A-frags + q2 in registers, b-loop barrier-free.
// ---------------------------------------------------------------------------
__global__ __launch_bounds__(256) void dist_kernel(
    const float* __restrict__ q, const uint4* __restrict__ pfrag,
    const float* __restrict__ p2, float* __restrict__ out) {
  int tid  = threadIdx.x;
  int wave = tid >> 6, lane = tid & 63;
  int l15  = lane & 15, quad = lane >> 4;
  int mtg  = wave & 1, ctg = wave >> 1;
  int q0   = blockIdx.x << 6;

  __shared__ float q2p[64][4];     // per-row, per-quad partial |q|^2

  // --- load A-fragments (Q) directly from global in fragment layout ---
  // A-layout: lane holds A[m=lane&15][k=quad*8+j] -> 8 consecutive floats.
  short8 af[2][4];
  #pragma unroll
  for (int mt2 = 0; mt2 < 2; ++mt2) {
    int rrow = (mtg * 2 + mt2) * 16 + l15;
    const float* qr = q + (size_t)(q0 + rrow) * DIM + quad * 8;
    float s = 0.f;
    #pragma unroll
    for (int k = 0; k < 4; ++k) {
      float4 x0 = *reinterpret_cast<const float4*>(qr + k * 32);
      float4 x1 = *reinterpret_cast<const float4*>(qr + k * 32 + 4);
      s += x0.x*x0.x + x0.y*x0.y + x0.z*x0.z + x0.w*x0.w
         + x1.x*x1.x + x1.y*x1.y + x1.z*x1.z + x1.w*x1.w;
      short8 a;
      a[0] = (short)f2bf(x0.x); a[1] = (short)f2bf(x0.y);
      a[2] = (short)f2bf(x0.z); a[3] = (short)f2bf(x0.w);
      a[4] = (short)f2bf(x1.x); a[5] = (short)f2bf(x1.y);
      a[6] = (short)f2bf(x1.z); a[7] = (short)f2bf(x1.w);
      af[mt2][k] = a;
    }
    if (ctg == 0) q2p[rrow][quad] = s;   // each row written by exactly one lane
  }
  __syncthreads();

  // q2 per accumulator row: C/D layout row = quad*4 + r (within m-tile)
  f32x4 q2r[2];
  #pragma unroll
  for (int mt2 = 0; mt2 < 2; ++mt2) {
    int r0 = (mtg * 2 + mt2) * 16 + quad * 4;
    f32x4 v;
    #pragma unroll
    for (int r = 0; r < 4; ++r) {
      float4 pp = *reinterpret_cast<const float4*>(&q2p[r0 + r][0]);
      v[r] = pp.x + pp.y + pp.z + pp.w;
    }
    q2r[mt2] = v;
  }

  f32x4 oacc[2][4];
  #pragma unroll
  for (int i = 0; i < 2; ++i)
    #pragma unroll
    for (int jj = 0; jj < 4; ++jj)
      oacc[i][jj] = (f32x4){0.f, 0.f, 0.f, 0.f};

  #pragma unroll 1
  for (int b = 0; b < NB; ++b) {
    float p2v[4];
    #pragma unroll
    for (int ct2 = 0; ct2 < 4; ++ct2)
      p2v[ct2] = p2[b * NCLS + (ctg * 4 + ct2) * 16 + l15];

    f32x4 qp[2][4];
    #pragma unroll
    for (int i = 0; i < 2; ++i)
      #pragma unroll
      for (int jj = 0; jj < 4; ++jj)
        qp[i][jj] = (f32x4){0.f, 0.f, 0.f, 0.f};

    #pragma unroll
    for (int ct2 = 0; ct2 < 4; ++ct2) {
      int ct = ctg * 4 + ct2;
      const uint4* bp = pfrag + (size_t)((b * 8 + ct) * 4) * 64 + lane;
      short8 bf0 = __builtin_bit_cast(short8, bp[0]);
      short8 bf1 = __builtin_bit_cast(short8, bp[64]);
      short8 bf2 = __builtin_bit_cast(short8, bp[128]);
      short8 bf3 = __builtin_bit_cast(short8, bp[192]);
      #pragma unroll
      for (int mt2 = 0; mt2 < 2; ++mt2) {
        qp[mt2][ct2] = __builtin_amdgcn_mfma_f32_16x16x32_bf16(af[mt2][0], bf0, qp[mt2][ct2], 0, 0, 0);
        qp[mt2][ct2] = __builtin_amdgcn_mfma_f32_16x16x32_bf16(af[mt2][1], bf1, qp[mt2][ct2], 0, 0, 0);
        qp[mt2][ct2] = __builtin_amdgcn_mfma_f32_16x16x32_bf16(af[mt2][2], bf2, qp[mt2][ct2], 0, 0, 0);
        qp[mt2][ct2] = __builtin_amdgcn_mfma_f32_16x16x32_bf16(af[mt2][3], bf3, qp[mt2][ct2], 0, 0, 0);
      }
    }

    #pragma unroll
    for (int mt2 = 0; mt2 < 2; ++mt2)
      #pragma unroll
      for (int ct2 = 0; ct2 < 4; ++ct2)
        #pragma unroll
        for (int r = 0; r < 4; ++r) {
          float t  = q2r[mt2][r] + p2v[ct2];
          float d2 = fmaf(-2.0f, qp[mt2][ct2][r], t);
          d2 = fmaxf(d2, 0.0f);
          oacc[mt2][ct2][r] += fast_sqrt(d2);
        }
  }

  // store: row = q0 + mt*16 + quad*4 + r, col = ct*16 + l15
  #pragma unroll
  for (int mt2 = 0; mt2 < 2; ++mt2)
    #pragma unroll
    for (int ct2 = 0; ct2 < 4; ++ct2) {
      int col = (ctg * 4 + ct2) * 16 + l15;
      #pragma unroll
      for (int r = 0; r < 4; ++r) {
        int row = q0 + (mtg * 2 + mt2) * 16 + quad * 4 + r;
        out[(size_t)row * NCLS + col] = -0.125f * oacc[mt2][ct2][r];
      }
    }
}

extern "C" void kernel_launch(void* const* d_in, const int* in_sizes, int n_in,
                              void* d_out, int out_size, void* d_ws, size_t ws_size,
                              hipStream_t stream) {
  const float* sup   = (const float*)d_in[0];   // [4096,128] f32
  // d_in[1] = support_labels (unused: sorted/balanced by construction)
  const float* query = (const float*)d_in[2];   // [65536,128] f32
  const int*   bidx  = (const int*)d_in[3];     // [8,128,32] i32
  float* out = (float*)d_out;                   // [65536,128] f32

  unsigned short* pfrag = (unsigned short*)d_ws;              // 8*128*128 bf16 = 256 KB
  float* p2 = (float*)((char*)d_ws + (size_t)NB * NCLS * DIM * 2); // 4 KB

  proto_kernel<<<NB * NCLS, 128, 0, stream>>>(sup, bidx, pfrag, p2);
  dist_kernel<<<NQ / 64, 256, 0, stream>>>(query, (const uint4*)pfrag, p2, out);
}